// Round 4
// baseline (72.395 us; speedup 1.0000x reference)
//
#include <hip/hip_runtime.h>

// ConvCNP encoder, GEMM formulation (R3).
// out[b,c,jy,ix] = sum_n Ey[b,jy,n] * w_c[b,n] * Ex[b,ix,n]   (c=1,2 / density)
//   Ex[b,ix,n] = exp(-0.5*(gx[ix]-X[b,n,0])^2),  Ey analogous with X[b,n,1]
//   w_0 = 1, w_1 = Y[:,0], w_2 = Y[:,1]
// Separable Gaussian => 12 tiny GEMMs (M=384, N=128, K=1024 per batch),
// done with mfma_f32_16x16x32_bf16, tables staged k-major in d_ws as bf16.
//
// R2 post-mortem: dur_us includes ~40.5us of harness d_ws re-poison fill
// (268MB, visible as the entire rocprof top-5); our kernel portion was ~28us
// and the VALU/exp path ran ~4-5x over its issue model. MFMA sidesteps it.

#define NCTX  1024
#define GPB   16384        // 128*128 grid points per batch
#define OUTB  (3 * GPB)    // floats per batch in out

typedef float f32x4  __attribute__((ext_vector_type(4)));
typedef short bf16x8 __attribute__((ext_vector_type(8)));   // 8 bf16 = 4 VGPRs

__device__ __forceinline__ float fast_exp2(float x) {
#if __has_builtin(__builtin_amdgcn_exp2f)
  return __builtin_amdgcn_exp2f(x);
#else
  return exp2f(x);
#endif
}

// float -> bf16 (round-to-nearest-even), no NaN/inf in our data
__device__ __forceinline__ unsigned short f2bf(float f) {
  union { float f; unsigned int u; } v; v.f = f;
  unsigned int r = v.u + 0x7FFFu + ((v.u >> 16) & 1u);
  return (unsigned short)(r >> 16);
}

// K1: build bf16 tables, k(=n)-major.
//   A [4][384][1024]: row (b, c*128+jy) = Ey[b,jy,:] * w_c   (rows 0..127: w=1)
//   B'[4][128][1024]: row (b, ix)       = Ex[b,ix,:]
// blocks 0..511 -> A rows (b,jy); 512..1023 -> B' rows (b,ix). 256 thr, 4 n each.
__global__ __launch_bounds__(256) void tables_kernel(
    const float* __restrict__ X, const float* __restrict__ Y,
    const float* __restrict__ grid,
    unsigned short* __restrict__ A, unsigned short* __restrict__ Bt)
{
  const float SC = 0.84932180028801907f;   // sqrt(0.5*log2(e))
  const int blk = blockIdx.x;
  const int t   = threadIdx.x;
  const bool isA = blk < 512;
  const int r   = isA ? blk : blk - 512;
  const int b   = r >> 7;
  const int row = r & 127;                         // jy (A) or ix (B')
  const float gs = (isA ? grid[2 * row + 1]        // gy[jy]
                        : grid[2 * (row * 128)])   // gx[ix]
                   * SC;

  const float2* Xb = (const float2*)(X + b * NCTX * 2);
  const int n0 = 4 * t;

  if (isA) {
    const float2* Yb = (const float2*)(Y + b * NCTX * 2);
    ushort4 o0, o1, o2;
#pragma unroll
    for (int i = 0; i < 4; ++i) {
      float2 x = Xb[n0 + i];
      float2 y = Yb[n0 + i];
      float d  = gs - SC * x.y;                    // uses X[...,1]
      float e  = fast_exp2(-(d * d));
      ((unsigned short*)&o0)[i] = f2bf(e);
      ((unsigned short*)&o1)[i] = f2bf(e * y.x);
      ((unsigned short*)&o2)[i] = f2bf(e * y.y);
    }
    unsigned short* a0 = A + (size_t)(b * 384 + row) * NCTX + n0;
    *(ushort4*)(a0)                 = o0;          // c=0 (density row)
    *(ushort4*)(a0 + 128 * NCTX)    = o1;          // c=1
    *(ushort4*)(a0 + 256 * NCTX)    = o2;          // c=2
  } else {
    ushort4 o;
#pragma unroll
    for (int i = 0; i < 4; ++i) {
      float2 x = Xb[n0 + i];
      float d  = gs - SC * x.x;                    // uses X[...,0]
      ((unsigned short*)&o)[i] = f2bf(fast_exp2(-(d * d)));
    }
    *(ushort4*)(Bt + (size_t)(b * 128 + row) * NCTX + n0) = o;
  }
}

// K2: one wave per 16x16 C-tile, full K=1024. Fragments loaded straight from
// global (k-major rows -> contiguous 16B per lane). No LDS, no barriers.
// A-frag: A[m = lane&15][k = (lane>>4)*8 + j]; B-frag symmetric with n=lane&15.
// C/D: row = (lane>>4)*4 + reg, col = lane&15 (verified m89/m91).
__global__ __launch_bounds__(64) void gemm_kernel(
    const unsigned short* __restrict__ A,
    const unsigned short* __restrict__ Bt,
    float* __restrict__ out)
{
  const int id   = blockIdx.x;          // 0..767
  const int b    = id / 192;            // 24 M-tiles * 8 N-tiles per batch
  const int rr   = id % 192;
  const int mt   = rr >> 3;             // 0..23  (rows mt*16 .. +15 of 384)
  const int nt   = rr & 7;              // 0..7   (cols nt*16 .. +15 of 128)
  const int lane = threadIdx.x;
  const int lo   = lane & 15;
  const int quad = lane >> 4;

  const bf16x8* ap = (const bf16x8*)(A  + (size_t)(b * 384 + mt * 16 + lo) * NCTX + quad * 8);
  const bf16x8* bp = (const bf16x8*)(Bt + (size_t)(b * 128 + nt * 16 + lo) * NCTX + quad * 8);

  f32x4 acc = {0.f, 0.f, 0.f, 0.f};
#pragma unroll 8
  for (int s = 0; s < 32; ++s) {        // K-step = 32 -> 4 bf16x8 units
    bf16x8 av = ap[4 * s];
    bf16x8 bv = bp[4 * s];
    acc = __builtin_amdgcn_mfma_f32_16x16x32_bf16(av, bv, acc, 0, 0, 0);
  }

  float* ob = out + (size_t)b * OUTB + nt * 16 + lo;
  const int grow0 = mt * 16 + quad * 4;
#pragma unroll
  for (int g = 0; g < 4; ++g)
    ob[(size_t)(grow0 + g) * 128] = acc[g];
}

// K3: in-place divide channels 1,2 by density. float4 per thread.
__global__ __launch_bounds__(256) void divide_kernel(float* __restrict__ out)
{
  const int id = blockIdx.x * 256 + threadIdx.x;  // 0..32767
  const int b  = id >> 13;
  const int r  = id & 8191;
  const int c  = r >> 12;                         // 0 -> ch1, 1 -> ch2
  const int p4 = r & 4095;
  float4* base = (float4*)(out + (size_t)b * OUTB);
  float4 d = base[p4];
  float4* vp = base + (size_t)(c + 1) * 4096 + p4;
  float4 v = *vp;
  v.x /= d.x; v.y /= d.y; v.z /= d.z; v.w /= d.w;
  *vp = v;
}

extern "C" void kernel_launch(void* const* d_in, const int* in_sizes, int n_in,
                              void* d_out, int out_size, void* d_ws, size_t ws_size,
                              hipStream_t stream) {
  const float* X    = (const float*)d_in[0];
  const float* Y    = (const float*)d_in[1];
  const float* grid = (const float*)d_in[2];
  float* out        = (float*)d_out;

  unsigned short* A  = (unsigned short*)d_ws;     // 4*384*1024 bf16 = 3 MB
  unsigned short* Bt = A + (size_t)4 * 384 * NCTX; // 4*128*1024 bf16 = 1 MB

  tables_kernel<<<dim3(1024), dim3(256), 0, stream>>>(X, Y, grid, A, Bt);
  gemm_kernel  <<<dim3(768),  dim3(64),  0, stream>>>(A, Bt, out);
  divide_kernel<<<dim3(128),  dim3(256), 0, stream>>>(out);
}

// Round 5
// 71.577 us; speedup vs baseline: 1.0114x; 1.0114x over previous
//
#include <hip/hip_runtime.h>

// ConvCNP encoder, fused-GEMM formulation (R4).
// out[b,c,jy,ix] = sum_n Ey[b,jy,n] * w_c[b,n] * Ex[b,ix,n]  (c=1,2 / density)
//   Ex[b,ix,n] = exp(-0.5*(gx[ix]-X[b,n,0])^2), Ey analogous with X[b,n,1]
//   w_0 = 1, w_1 = Y[:,0], w_2 = Y[:,1]
// K1 builds bf16 tables A[4][384][1024] (Ey*w_c) and Bt[4][128][1024] (Ex),
// K2: one wave per 16x16 (jy,ix) patch accumulates ALL 3 channels (3 MFMA
// chains share each B-fragment), divides in-register, stores final output.
//
// Measurement model (R0-R3 cross-fit): dur_us ~= 63-67us fixed harness work
// per replay (256MiB d_ws poison fill = the ~40us fillBuffer in every rocprof
// top-5 slot) + our kernel time (~5us now). R4 removes one launch + K3's
// global density round-trip + 1/3 of K2's table loads.

#define NCTX  1024
#define GPB   16384        // 128*128 grid points per batch
#define OUTB  (3 * GPB)    // floats per batch in out

typedef float f32x4  __attribute__((ext_vector_type(4)));
typedef short bf16x8 __attribute__((ext_vector_type(8)));   // 8 bf16 = 4 VGPRs

__device__ __forceinline__ float fast_exp2(float x) {
#if __has_builtin(__builtin_amdgcn_exp2f)
  return __builtin_amdgcn_exp2f(x);
#else
  return exp2f(x);
#endif
}

// float -> bf16 round-to-nearest-even (no NaN/inf in this data)
__device__ __forceinline__ unsigned short f2bf(float f) {
  union { float f; unsigned int u; } v; v.f = f;
  unsigned int r = v.u + 0x7FFFu + ((v.u >> 16) & 1u);
  return (unsigned short)(r >> 16);
}

// K1: build bf16 tables, k(=n)-major.
//   A [4][384][1024]: row (b, c*128+jy) = Ey[b,jy,:] * w_c  (rows 0..127: w=1)
//   Bt[4][128][1024]: row (b, ix)       = Ex[b,ix,:]
// blocks 0..511 -> A rows (b,jy); 512..1023 -> Bt rows (b,ix). 256 thr, 4 n each.
__global__ __launch_bounds__(256) void tables_kernel(
    const float* __restrict__ X, const float* __restrict__ Y,
    const float* __restrict__ grid,
    unsigned short* __restrict__ A, unsigned short* __restrict__ Bt)
{
  const float SC = 0.84932180028801907f;   // sqrt(0.5*log2(e))
  const int blk = blockIdx.x;
  const int t   = threadIdx.x;
  const bool isA = blk < 512;
  const int r   = isA ? blk : blk - 512;
  const int b   = r >> 7;
  const int row = r & 127;                         // jy (A) or ix (Bt)
  const float gs = (isA ? grid[2 * row + 1]        // gy[jy]
                        : grid[2 * (row * 128)])   // gx[ix]
                   * SC;

  const float2* Xb = (const float2*)(X + b * NCTX * 2);
  const int n0 = 4 * t;

  if (isA) {
    const float2* Yb = (const float2*)(Y + b * NCTX * 2);
    ushort4 o0, o1, o2;
#pragma unroll
    for (int i = 0; i < 4; ++i) {
      float2 x = Xb[n0 + i];
      float2 y = Yb[n0 + i];
      float d  = gs - SC * x.y;                    // uses X[...,1]
      float e  = fast_exp2(-(d * d));
      ((unsigned short*)&o0)[i] = f2bf(e);
      ((unsigned short*)&o1)[i] = f2bf(e * y.x);
      ((unsigned short*)&o2)[i] = f2bf(e * y.y);
    }
    unsigned short* a0 = A + (size_t)(b * 384 + row) * NCTX + n0;
    *(ushort4*)(a0)              = o0;             // c=0 (density rows)
    *(ushort4*)(a0 + 128 * NCTX) = o1;             // c=1
    *(ushort4*)(a0 + 256 * NCTX) = o2;             // c=2
  } else {
    ushort4 o;
#pragma unroll
    for (int i = 0; i < 4; ++i) {
      float2 x = Xb[n0 + i];
      float d  = gs - SC * x.x;                    // uses X[...,0]
      ((unsigned short*)&o)[i] = f2bf(fast_exp2(-(d * d)));
    }
    *(ushort4*)(Bt + (size_t)(b * 128 + row) * NCTX + n0) = o;
  }
}

// K2: one wave per (b, jyt, ixt) 16x16 patch, all 3 channels, full K=1024.
// Fragments straight from global (k-major rows -> contiguous 16B/lane; the
// 4 quad-groups of a row cover one 64B line). No LDS, no barriers.
// A-frag: A[m=lane&15][k=(lane>>4)*8+j]; C/D: row=(lane>>4)*4+reg, col=lane&15.
__global__ __launch_bounds__(64) void gemm_div_kernel(
    const unsigned short* __restrict__ A,
    const unsigned short* __restrict__ Bt,
    float* __restrict__ out)
{
  const int id   = blockIdx.x;          // 0..255 = b*64 + jyt*8 + ixt
  const int b    = id >> 6;
  const int jyt  = (id >> 3) & 7;
  const int ixt  = id & 7;
  const int lane = threadIdx.x;
  const int lo   = lane & 15;
  const int quad = lane >> 4;

  const size_t koff = (size_t)quad * 8;
  const unsigned short* a0 = A  + ((size_t)(b * 384) + jyt * 16 + lo) * NCTX + koff;
  const unsigned short* bp = Bt + ((size_t)(b * 128) + ixt * 16 + lo) * NCTX + koff;

  f32x4 acc0 = {0.f,0.f,0.f,0.f}, acc1 = acc0, acc2 = acc0;
#pragma unroll 4
  for (int s = 0; s < 32; ++s) {        // K-step 32 -> row offset s*32 shorts
    const size_t o = (size_t)s * 32;
    bf16x8 bv  = *(const bf16x8*)(bp + o);
    bf16x8 a0v = *(const bf16x8*)(a0 + o);
    bf16x8 a1v = *(const bf16x8*)(a0 + 128 * NCTX + o);
    bf16x8 a2v = *(const bf16x8*)(a0 + 256 * NCTX + o);
    acc0 = __builtin_amdgcn_mfma_f32_16x16x32_bf16(a0v, bv, acc0, 0, 0, 0);
    acc1 = __builtin_amdgcn_mfma_f32_16x16x32_bf16(a1v, bv, acc1, 0, 0, 0);
    acc2 = __builtin_amdgcn_mfma_f32_16x16x32_bf16(a2v, bv, acc2, 0, 0, 0);
  }

  // rows of the patch: jy = jyt*16 + quad*4 + g; cols: ix = ixt*16 + lo
  float* ob = out + (size_t)b * OUTB + (jyt * 16 + quad * 4) * 128 + ixt * 16 + lo;
#pragma unroll
  for (int g = 0; g < 4; ++g) {
    float d = acc0[g];
    ob[(size_t)g * 128]               = d;
    ob[(size_t)g * 128 + GPB]         = acc1[g] / d;
    ob[(size_t)g * 128 + 2 * GPB]     = acc2[g] / d;
  }
}

extern "C" void kernel_launch(void* const* d_in, const int* in_sizes, int n_in,
                              void* d_out, int out_size, void* d_ws, size_t ws_size,
                              hipStream_t stream) {
  const float* X    = (const float*)d_in[0];
  const float* Y    = (const float*)d_in[1];
  const float* grid = (const float*)d_in[2];
  float* out        = (float*)d_out;

  unsigned short* A  = (unsigned short*)d_ws;       // 4*384*1024 bf16 = 3 MB
  unsigned short* Bt = A + (size_t)4 * 384 * NCTX;  // 4*128*1024 bf16 = 1 MB

  tables_kernel  <<<dim3(1024), dim3(256), 0, stream>>>(X, Y, grid, A, Bt);
  gemm_div_kernel<<<dim3(256),  dim3(64),  0, stream>>>(A, Bt, out);
}